// Round 3
// baseline (6361.569 us; speedup 1.0000x reference)
//
#include <hip/hip_runtime.h>
#include <hip/hip_fp16.h>

// LSTM autoencoder B=256,S=512,D=64,H=128. 1 row/WG, 256 WGs, 512 thr = gate cols.
// Gate-interleaved columns: thread tid -> hidden j=tid>>2, gate r=tid&3 (i,f,g,o).
// In-wave cell update via DPP quad_perm (no LDS scratch, no tail phases).
// enc: 1 barrier/step; dec: 2 barriers/step, fc fused into next step via W'=Wih0·fcW.

typedef _Float16 h2 __attribute__((ext_vector_type(2)));
typedef _Float16 h8 __attribute__((ext_vector_type(8)));

#define Bsz 256
#define Ssz 512
#define Dsz 64
#define Hsz 128
#define G4 512
#define NT 512

__device__ __forceinline__ float fdot2f(h2 a, h2 b, float c) {
#if __has_builtin(__builtin_amdgcn_fdot2)
  return __builtin_amdgcn_fdot2(a, b, c, false);
#else
  return c + (float)a[0] * (float)b[0] + (float)a[1] * (float)b[1];
#endif
}

__device__ __forceinline__ float dot8(h8 v, h8 w, float acc) {
  h2 v0 = __builtin_shufflevector(v, v, 0, 1);
  h2 v1 = __builtin_shufflevector(v, v, 2, 3);
  h2 v2 = __builtin_shufflevector(v, v, 4, 5);
  h2 v3 = __builtin_shufflevector(v, v, 6, 7);
  h2 w0 = __builtin_shufflevector(w, w, 0, 1);
  h2 w1 = __builtin_shufflevector(w, w, 2, 3);
  h2 w2 = __builtin_shufflevector(w, w, 4, 5);
  h2 w3 = __builtin_shufflevector(w, w, 6, 7);
  acc = fdot2f(v0, w0, acc);
  acc = fdot2f(v1, w1, acc);
  acc = fdot2f(v2, w2, acc);
  acc = fdot2f(v3, w3, acc);
  return acc;
}

__device__ __forceinline__ float sigm(float v) { return 1.f / (1.f + __expf(-v)); }
__device__ __forceinline__ float tanh_f(float v) { return 2.f / (1.f + __expf(-2.f * v)) - 1.f; }

// quad_perm DPP: xor1=0xB1 [1,0,3,2], xor2=0x4E [2,3,0,1], xor3=0x1B [3,2,1,0]
template <int C, int M>
__device__ __forceinline__ float qperm(float x) {
#if __has_builtin(__builtin_amdgcn_mov_dpp)
  int i = __builtin_amdgcn_mov_dpp(__builtin_bit_cast(int, x), C, 0xf, 0xf, true);
  return __builtin_bit_cast(float, i);
#else
  return __shfl_xor(x, M, 64);
#endif
}

__device__ __forceinline__ int permcol(int n) { return (n & 3) * 128 + (n >> 2); }

__global__ void __launch_bounds__(NT, 2)
enc_kernel(const float* __restrict__ x,
           const h8* __restrict__ wih0, const h8* __restrict__ whh0,
           const h8* __restrict__ wih1, const h8* __restrict__ whh1,
           const float* __restrict__ b0v, const float* __restrict__ b1v,
           float* __restrict__ st) {
  __shared__ h8 s_wih0[8 * G4];      // 64 KiB streamed weight (smallest)
  __shared__ h8 H0[2][16], H1[2][16], xp[2][8];

  const int tid = threadIdx.x;
  const int row = blockIdx.x;
  const int r = tid & 3;
  const int j = tid >> 2;

  h8 Whh0[16], Wih1[16], Whh1[16];
#pragma unroll
  for (int k = 0; k < 16; ++k) Whh0[k] = whh0[k * G4 + tid];
#pragma unroll
  for (int k = 0; k < 16; ++k) Wih1[k] = wih1[k * G4 + tid];
#pragma unroll
  for (int k = 0; k < 16; ++k) Whh1[k] = whh1[k * G4 + tid];
  for (int i = tid; i < 8 * G4; i += NT) s_wih0[i] = wih0[i];

  if (tid < 128) ((_Float16*)H0[0])[tid] = (_Float16)0.f;
  else if (tid < 256) ((_Float16*)H1[0])[tid - 128] = (_Float16)0.f;
  else if (tid < 320)
    ((_Float16*)xp[0])[tid - 256] = (_Float16)x[(size_t)row * Ssz * Dsz + (tid - 256)];

  const float b0 = b0v[tid], b1 = b1v[tid];
  const float Sc = (r == 2) ? 2.f : 1.f;
  const float Kc = (r == 2) ? 2.f : 1.f;
  const float Dc = (r == 2) ? -1.f : 0.f;
  float c0 = 0.f, c1 = 0.f, h0_last = 0.f, h1_last = 0.f;
  __syncthreads();

  for (int t = 0; t < Ssz; ++t) {
    const h8* H0r = H0[t & 1];
    h8* H0w = H0[(t + 1) & 1];
    // x(t+1) prefetch by wave 0 (issue early, LDS-write late)
    float xv = 0.f;
    const bool pf = (tid < Dsz) && (t + 1 < Ssz);
    if (pf) xv = x[((size_t)row * Ssz + (t + 1)) * Dsz + tid];
    // P1: layer0 gate
    float a = b0;
#pragma unroll
    for (int k = 0; k < 8; ++k) a = dot8(xp[t & 1][k], s_wih0[k * G4 + tid], a);
#pragma unroll
    for (int k = 0; k < 16; ++k) a = dot8(H0r[k], Whh0[k], a);
    if (pf) ((_Float16*)xp[(t + 1) & 1])[tid] = (_Float16)xv;
    float n = Sc * sigm(Kc * a) + Dc;
    float vf = qperm<0xB1, 1>(n), vg = qperm<0x4E, 2>(n), vo = qperm<0x1B, 3>(n);
    if (r == 0) {
      c0 = vf * c0 + n * vg;
      float h = vo * tanh_f(c0);
      h0_last = h;
      ((_Float16*)H0w)[j] = (_Float16)h;
    }
    __syncthreads();
    // P2: layer1 gate
    const h8* H1r = H1[t & 1];
    h8* H1w = H1[(t + 1) & 1];
    float a1 = b1;
#pragma unroll
    for (int k = 0; k < 16; ++k) a1 = dot8(H0w[k], Wih1[k], a1);
#pragma unroll
    for (int k = 0; k < 16; ++k) a1 = dot8(H1r[k], Whh1[k], a1);
    n = Sc * sigm(Kc * a1) + Dc;
    vf = qperm<0xB1, 1>(n); vg = qperm<0x4E, 2>(n); vo = qperm<0x1B, 3>(n);
    if (r == 0) {
      c1 = vf * c1 + n * vg;
      float h = vo * tanh_f(c1);
      h1_last = h;
      ((_Float16*)H1w)[j] = (_Float16)h;
    }
    // no barrier needed: next P1 touches only H0[t&1] (free) and reads H0w (pre-B1)
  }
  if (r == 0) {
    st[0 * Bsz * Hsz + row * Hsz + j] = h0_last;
    st[1 * Bsz * Hsz + row * Hsz + j] = c0;
    st[2 * Bsz * Hsz + row * Hsz + j] = h1_last;
    st[3 * Bsz * Hsz + row * Hsz + j] = c1;
  }
}

__global__ void __launch_bounds__(NT, 2)
dec_kernel(const h8* __restrict__ wprime, const h8* __restrict__ whh0,
           const h8* __restrict__ wih1, const h8* __restrict__ whh1,
           const h8* __restrict__ fcpk,
           const float* __restrict__ b00v, const float* __restrict__ b0tv,
           const float* __restrict__ b1v, const float* __restrict__ fcb,
           const float* __restrict__ st, float* __restrict__ out) {
  __shared__ h8 s_whh1[16 * G4];     // 128 KiB streamed weight
  __shared__ h8 H0[2][16], H1[2][16];

  const int tid = threadIdx.x;
  const int row = blockIdx.x;
  const int r = tid & 3;
  const int j = tid >> 2;
  const int j8 = tid >> 3;           // fc output column
  const int kp = (tid & 7) * 2;      // fc k-chunks for this thread

  h8 Wp[16], Whh0[16], Wih1[16];
#pragma unroll
  for (int k = 0; k < 16; ++k) Wp[k] = wprime[k * G4 + tid];
#pragma unroll
  for (int k = 0; k < 16; ++k) Whh0[k] = whh0[k * G4 + tid];
#pragma unroll
  for (int k = 0; k < 16; ++k) Wih1[k] = wih1[k * G4 + tid];
  const h8 Fc0 = fcpk[tid * 2];
  const h8 Fc1 = fcpk[tid * 2 + 1];
  for (int i = tid; i < 16 * G4; i += NT) s_whh1[i] = whh1[i];

  float c0 = 0.f, c1 = 0.f;
  if (tid < 128)
    ((_Float16*)H0[0])[tid] = (_Float16)st[0 * Bsz * Hsz + row * Hsz + tid];
  else if (tid < 256)
    ((_Float16*)H1[0])[tid - 128] = (_Float16)st[2 * Bsz * Hsz + row * Hsz + (tid - 128)];
  if (r == 0) {
    c0 = st[1 * Bsz * Hsz + row * Hsz + j];
    c1 = st[3 * Bsz * Hsz + row * Hsz + j];
  }
  const float b00 = b00v[tid], b0t = b0tv[tid], b1 = b1v[tid];
  const float fcbj = fcb[j8];
  const float Sc = (r == 2) ? 2.f : 1.f;
  const float Kc = (r == 2) ? 2.f : 1.f;
  const float Dc = (r == 2) ? -1.f : 0.f;
  __syncthreads();

  for (int t = 0; t < Ssz; ++t) {
    const h8* H0r = H0[t & 1];
    h8* H0w = H0[(t + 1) & 1];
    const h8* H1r = H1[t & 1];       // h1(t-1)
    float a;
    if (t > 0) {
      // fused feedback: y(t-1)@Wih0 == h1(t-1)@W' + b'
      a = b0t;
#pragma unroll
      for (int k = 0; k < 16; ++k) a = dot8(H1r[k], Wp[k], a);
      // side-work: out(t-1) = h1(t-1)@fcW^T + fcb  (off critical path)
      float op = dot8(H1r[kp], Fc0, 0.f);
      op = dot8(H1r[kp + 1], Fc1, op);
      op += __shfl_xor(op, 1);
      op += __shfl_xor(op, 2);
      op += __shfl_xor(op, 4);
      if ((tid & 7) == 0)
        out[((size_t)row * Ssz + (t - 1)) * Dsz + j8] = op + fcbj;
    } else {
      a = b00;                        // y(0)=0: no W' term, no b'
    }
#pragma unroll
    for (int k = 0; k < 16; ++k) a = dot8(H0r[k], Whh0[k], a);
    float n = Sc * sigm(Kc * a) + Dc;
    float vf = qperm<0xB1, 1>(n), vg = qperm<0x4E, 2>(n), vo = qperm<0x1B, 3>(n);
    if (r == 0) {
      c0 = vf * c0 + n * vg;
      ((_Float16*)H0w)[j] = (_Float16)(vo * tanh_f(c0));
    }
    __syncthreads();
    h8* H1w = H1[(t + 1) & 1];
    float a1 = b1;
#pragma unroll
    for (int k = 0; k < 16; ++k) a1 = dot8(H0w[k], Wih1[k], a1);
#pragma unroll
    for (int k = 0; k < 16; ++k) a1 = dot8(H1r[k], s_whh1[k * G4 + tid], a1);
    n = Sc * sigm(Kc * a1) + Dc;
    vf = qperm<0xB1, 1>(n); vg = qperm<0x4E, 2>(n); vo = qperm<0x1B, 3>(n);
    if (r == 0) {
      c1 = vf * c1 + n * vg;
      ((_Float16*)H1w)[j] = (_Float16)(vo * tanh_f(c1));
    }
    __syncthreads();
  }
  // tail: out(S-1)
  const h8* H1f = H1[Ssz & 1];
  float op = dot8(H1f[kp], Fc0, 0.f);
  op = dot8(H1f[kp + 1], Fc1, op);
  op += __shfl_xor(op, 1);
  op += __shfl_xor(op, 2);
  op += __shfl_xor(op, 4);
  if ((tid & 7) == 0)
    out[((size_t)row * Ssz + (Ssz - 1)) * Dsz + j8] = op + fcbj;
}

// ---- prep kernels ----

// fp32 [512][K] row-major -> f16 h8 [K/8][512], gate-interleaved column perm
__global__ void pack8p_kernel(const float* __restrict__ W, h8* __restrict__ o, int K) {
  int idx = blockIdx.x * 256 + threadIdx.x;
  int tot = (K >> 3) * G4;
  if (idx >= tot) return;
  int k8 = idx >> 9, np = idx & 511;
  const float* p = W + permcol(np) * K + 8 * k8;
  h8 v;
#pragma unroll
  for (int e = 0; e < 8; ++e) v[e] = (_Float16)p[e];
  o[idx] = v;
}

// W'[h][col] = sum_d Wih0_dec[col][d] * fcW[d][h]; packed [16][512] h8, permuted cols
__global__ void wprime_kernel(const float* __restrict__ wih0d, const float* __restrict__ fcw,
                              h8* __restrict__ o) {
  int idx = blockIdx.x * 256 + threadIdx.x;
  if (idx >= 16 * G4) return;
  int k8 = idx >> 9, np = idx & 511;
  int col = permcol(np);
  h8 v;
#pragma unroll
  for (int e = 0; e < 8; ++e) {
    int h = 8 * k8 + e;
    float s = 0.f;
    for (int d = 0; d < 64; ++d) s += wih0d[col * 64 + d] * fcw[d * 128 + h];
    v[e] = (_Float16)s;
  }
  o[idx] = v;
}

// per-thread fc register chunks: o[tid*2+c] = fcW[j8][ (2p+c)*8 .. +8 ), j8=tid>>3,p=tid&7
__global__ void fcpack_kernel(const float* __restrict__ fcw, h8* __restrict__ o) {
  int idx = blockIdx.x * 256 + threadIdx.x;
  if (idx >= 2 * NT) return;
  int tt = idx >> 1, c = idx & 1;
  int jj = tt >> 3, k = (tt & 7) * 2 + c;
  h8 v;
#pragma unroll
  for (int e = 0; e < 8; ++e) v[e] = (_Float16)fcw[jj * 128 + k * 8 + e];
  o[idx] = v;
}

__global__ void biasp_kernel(const float* __restrict__ a, const float* __restrict__ b,
                             float* __restrict__ o) {
  int n = blockIdx.x * 256 + threadIdx.x;
  if (n >= G4) return;
  int c = permcol(n);
  o[n] = a[c] + b[c];
}

// b0t[n] = b00[n] + sum_d fcb[d]*Wih0_dec[permcol(n)][d]
__global__ void bprime_kernel(const float* __restrict__ b00, const float* __restrict__ wih0d,
                              const float* __restrict__ fcb, float* __restrict__ o) {
  int n = blockIdx.x * 256 + threadIdx.x;
  if (n >= G4) return;
  int c = permcol(n);
  float s = 0.f;
  for (int d = 0; d < 64; ++d) s += fcb[d] * wih0d[c * 64 + d];
  o[n] = b00[n] + s;
}

extern "C" void kernel_launch(void* const* d_in, const int* in_sizes, int n_in,
                              void* d_out, int out_size, void* d_ws, size_t ws_size,
                              hipStream_t stream) {
  (void)in_sizes; (void)n_in; (void)out_size; (void)ws_size;
  char* ws = (char*)d_ws;
  size_t off = 0;
  auto take = [&](size_t bytes) {
    char* p = ws + off;
    off += (bytes + 255) & ~(size_t)255;
    return p;
  };

  h8* e0_wih = (h8*)take(8 * 512 * 16);
  h8* e0_whh = (h8*)take(16 * 512 * 16);
  h8* e1_wih = (h8*)take(16 * 512 * 16);
  h8* e1_whh = (h8*)take(16 * 512 * 16);
  h8* d_wp   = (h8*)take(16 * 512 * 16);
  h8* d0_whh = (h8*)take(16 * 512 * 16);
  h8* d1_wih = (h8*)take(16 * 512 * 16);
  h8* d1_whh = (h8*)take(16 * 512 * 16);
  h8* fcpk   = (h8*)take(2 * 512 * 16);
  float* b_e0  = (float*)take(512 * 4);
  float* b_e1  = (float*)take(512 * 4);
  float* b_d00 = (float*)take(512 * 4);
  float* b_d0t = (float*)take(512 * 4);
  float* b_d1  = (float*)take(512 * 4);
  float* st    = (float*)take(4 * Bsz * Hsz * 4);

  const float* x = (const float*)d_in[0];

  pack8p_kernel<<<16, 256, 0, stream>>>((const float*)d_in[1], e0_wih, 64);
  pack8p_kernel<<<32, 256, 0, stream>>>((const float*)d_in[2], e0_whh, 128);
  pack8p_kernel<<<32, 256, 0, stream>>>((const float*)d_in[5], e1_wih, 128);
  pack8p_kernel<<<32, 256, 0, stream>>>((const float*)d_in[6], e1_whh, 128);
  wprime_kernel<<<32, 256, 0, stream>>>((const float*)d_in[9], (const float*)d_in[17], d_wp);
  pack8p_kernel<<<32, 256, 0, stream>>>((const float*)d_in[10], d0_whh, 128);
  pack8p_kernel<<<32, 256, 0, stream>>>((const float*)d_in[13], d1_wih, 128);
  pack8p_kernel<<<32, 256, 0, stream>>>((const float*)d_in[14], d1_whh, 128);
  fcpack_kernel<<<4, 256, 0, stream>>>((const float*)d_in[17], fcpk);

  biasp_kernel<<<2, 256, 0, stream>>>((const float*)d_in[3], (const float*)d_in[4], b_e0);
  biasp_kernel<<<2, 256, 0, stream>>>((const float*)d_in[7], (const float*)d_in[8], b_e1);
  biasp_kernel<<<2, 256, 0, stream>>>((const float*)d_in[11], (const float*)d_in[12], b_d00);
  biasp_kernel<<<2, 256, 0, stream>>>((const float*)d_in[15], (const float*)d_in[16], b_d1);
  bprime_kernel<<<2, 256, 0, stream>>>(b_d00, (const float*)d_in[9], (const float*)d_in[18], b_d0t);

  enc_kernel<<<Bsz, NT, 0, stream>>>(x, e0_wih, e0_whh, e1_wih, e1_whh, b_e0, b_e1, st);
  dec_kernel<<<Bsz, NT, 0, stream>>>(d_wp, d0_whh, d1_wih, d1_whh, fcpk,
                                     b_d00, b_d0t, b_d1, (const float*)d_in[18], st,
                                     (float*)d_out);
}

// Round 4
// 5553.704 us; speedup vs baseline: 1.1455x; 1.1455x over previous
//
#include <hip/hip_runtime.h>
#include <hip/hip_fp16.h>

// LSTM autoencoder B=256,S=512,D=64,H=128. 1 row/WG, 256 WGs, 512 thr = gate cols.
// Gate-interleaved columns: thread tid -> hidden j=tid>>2, gate r=tid&3 (i,f,g,o).
// ALL weights pinned on-chip: 192 VGPRs/thread (3 matrices) + 64-128KB LDS (1 matrix).
// amdgpu_waves_per_eu(2,2) forces the 256-VGPR budget (R3 failed at the default 128 cap).
// enc: 1 barrier/step; dec: 2 barriers/step, feedback fused via W'=Wih0_dec·fcW;
// fc projection done by a separate epilogue kernel, in-place in d_out.

typedef _Float16 h2 __attribute__((ext_vector_type(2)));
typedef _Float16 h8 __attribute__((ext_vector_type(8)));

#define Bsz 256
#define Ssz 512
#define Dsz 64
#define Hsz 128
#define G4 512
#define NT 512

__device__ __forceinline__ float fdot2f(h2 a, h2 b, float c) {
#if __has_builtin(__builtin_amdgcn_fdot2)
  return __builtin_amdgcn_fdot2(a, b, c, false);
#else
  return c + (float)a[0] * (float)b[0] + (float)a[1] * (float)b[1];
#endif
}

__device__ __forceinline__ float dot8(h8 v, h8 w, float acc) {
  h2 v0 = __builtin_shufflevector(v, v, 0, 1);
  h2 v1 = __builtin_shufflevector(v, v, 2, 3);
  h2 v2 = __builtin_shufflevector(v, v, 4, 5);
  h2 v3 = __builtin_shufflevector(v, v, 6, 7);
  h2 w0 = __builtin_shufflevector(w, w, 0, 1);
  h2 w1 = __builtin_shufflevector(w, w, 2, 3);
  h2 w2 = __builtin_shufflevector(w, w, 4, 5);
  h2 w3 = __builtin_shufflevector(w, w, 6, 7);
  acc = fdot2f(v0, w0, acc);
  acc = fdot2f(v1, w1, acc);
  acc = fdot2f(v2, w2, acc);
  acc = fdot2f(v3, w3, acc);
  return acc;
}

__device__ __forceinline__ float sigm(float v) { return 1.f / (1.f + __expf(-v)); }
__device__ __forceinline__ float tanh_f(float v) { return 2.f / (1.f + __expf(-2.f * v)) - 1.f; }

// quad_perm DPP: 0xB1=[1,0,3,2](xor1), 0x4E=[2,3,0,1](xor2), 0x1B=[3,2,1,0](xor3)
template <int C, int M>
__device__ __forceinline__ float qperm(float x) {
#if __has_builtin(__builtin_amdgcn_mov_dpp)
  int i = __builtin_amdgcn_mov_dpp(__builtin_bit_cast(int, x), C, 0xf, 0xf, true);
  return __builtin_bit_cast(float, i);
#else
  return __shfl_xor(x, M, 64);
#endif
}

__device__ __forceinline__ int permcol(int n) { return (n & 3) * 128 + (n >> 2); }

__global__ void __launch_bounds__(NT) __attribute__((amdgpu_waves_per_eu(2, 2)))
enc_kernel(const float* __restrict__ x,
           const h8* __restrict__ wih0, const h8* __restrict__ whh0,
           const h8* __restrict__ wih1, const h8* __restrict__ whh1,
           const float* __restrict__ b0v, const float* __restrict__ b1v,
           float* __restrict__ st) {
  __shared__ h8 s_wih0[8 * G4];      // 64 KiB (smallest matrix in LDS)
  __shared__ h8 H0[2][16], H1[2][16], xp[2][8];

  const int tid = threadIdx.x;
  const int row = blockIdx.x;
  const int r = tid & 3;
  const int j = tid >> 2;

  h8 Whh0[16], Wih1[16], Whh1[16];   // 192 VGPRs, must stay resident
#pragma unroll
  for (int k = 0; k < 16; ++k) Whh0[k] = whh0[k * G4 + tid];
#pragma unroll
  for (int k = 0; k < 16; ++k) Wih1[k] = wih1[k * G4 + tid];
#pragma unroll
  for (int k = 0; k < 16; ++k) Whh1[k] = whh1[k * G4 + tid];
  for (int i = tid; i < 8 * G4; i += NT) s_wih0[i] = wih0[i];

  if (tid < 128) ((_Float16*)H0[0])[tid] = (_Float16)0.f;
  else if (tid < 256) ((_Float16*)H1[0])[tid - 128] = (_Float16)0.f;
  else if (tid < 320)
    ((_Float16*)xp[0])[tid - 256] = (_Float16)x[(size_t)row * Ssz * Dsz + (tid - 256)];

  const float b0 = b0v[tid], b1 = b1v[tid];
  const float Sc = (r == 2) ? 2.f : 1.f;
  const float Kc = (r == 2) ? 2.f : 1.f;
  const float Dc = (r == 2) ? -1.f : 0.f;
  float c0 = 0.f, c1 = 0.f;
  __syncthreads();

  for (int t = 0; t < Ssz; ++t) {
    const h8* H0r = H0[t & 1];
    h8* H0w = H0[(t + 1) & 1];
    // x(t+1) prefetch: issue early, LDS-write late
    float xv = 0.f;
    const bool pf = (tid < Dsz) && (t + 1 < Ssz);
    if (pf) xv = x[((size_t)row * Ssz + (t + 1)) * Dsz + tid];
    // P1: layer0 gates
    float a[4] = {b0, 0.f, 0.f, 0.f};
#pragma unroll
    for (int k = 0; k < 8; ++k) a[k & 3] = dot8(xp[t & 1][k], s_wih0[k * G4 + tid], a[k & 3]);
#pragma unroll
    for (int k = 0; k < 16; ++k) a[k & 3] = dot8(H0r[k], Whh0[k], a[k & 3]);
    if (pf) ((_Float16*)xp[(t + 1) & 1])[tid] = (_Float16)xv;
    float av = (a[0] + a[1]) + (a[2] + a[3]);
    float n = Sc * sigm(Kc * av) + Dc;
    float vf = qperm<0xB1, 1>(n), vg = qperm<0x4E, 2>(n), vo = qperm<0x1B, 3>(n);
    if (r == 0) {
      c0 = vf * c0 + n * vg;
      ((_Float16*)H0w)[j] = (_Float16)(vo * tanh_f(c0));
    }
    __syncthreads();
    // P2: layer1 gates
    const h8* H1r = H1[t & 1];
    h8* H1w = H1[(t + 1) & 1];
    float a1[4] = {b1, 0.f, 0.f, 0.f};
#pragma unroll
    for (int k = 0; k < 16; ++k) a1[k & 3] = dot8(H0w[k], Wih1[k], a1[k & 3]);
#pragma unroll
    for (int k = 0; k < 16; ++k) a1[k & 3] = dot8(H1r[k], Whh1[k], a1[k & 3]);
    av = (a1[0] + a1[1]) + (a1[2] + a1[3]);
    n = Sc * sigm(Kc * av) + Dc;
    vf = qperm<0xB1, 1>(n); vg = qperm<0x4E, 2>(n); vo = qperm<0x1B, 3>(n);
    if (r == 0) {
      c1 = vf * c1 + n * vg;
      ((_Float16*)H1w)[j] = (_Float16)(vo * tanh_f(c1));
    }
    // no barrier: next P1's reads/writes are hazard-free (double buffers + B1)
  }
  if (r == 0) {
    st[0 * Bsz * Hsz + row * Hsz + j] = (float)((_Float16*)H0[Ssz & 1])[j];
    st[1 * Bsz * Hsz + row * Hsz + j] = c0;
    st[2 * Bsz * Hsz + row * Hsz + j] = (float)((_Float16*)H1[Ssz & 1])[j];
    st[3 * Bsz * Hsz + row * Hsz + j] = c1;
  }
}

__global__ void __launch_bounds__(NT) __attribute__((amdgpu_waves_per_eu(2, 2)))
dec_kernel(const h8* __restrict__ wprime, const h8* __restrict__ whh0,
           const h8* __restrict__ wih1, const h8* __restrict__ whh1,
           const float* __restrict__ b00v, const float* __restrict__ b0tv,
           const float* __restrict__ b1v, const float* __restrict__ st,
           _Float16* __restrict__ h1g) {
  __shared__ h8 s_whh1[16 * G4];     // 128 KiB
  __shared__ h8 H0[2][16], H1[2][16];

  const int tid = threadIdx.x;
  const int row = blockIdx.x;
  const int r = tid & 3;
  const int j = tid >> 2;

  h8 Wp[16], Whh0[16], Wih1[16];     // 192 VGPRs, must stay resident
#pragma unroll
  for (int k = 0; k < 16; ++k) Wp[k] = wprime[k * G4 + tid];
#pragma unroll
  for (int k = 0; k < 16; ++k) Whh0[k] = whh0[k * G4 + tid];
#pragma unroll
  for (int k = 0; k < 16; ++k) Wih1[k] = wih1[k * G4 + tid];
  for (int i = tid; i < 16 * G4; i += NT) s_whh1[i] = whh1[i];

  float c0 = 0.f, c1 = 0.f;
  if (tid < 128)
    ((_Float16*)H0[0])[tid] = (_Float16)st[0 * Bsz * Hsz + row * Hsz + tid];
  else if (tid < 256)
    ((_Float16*)H1[0])[tid - 128] = (_Float16)st[2 * Bsz * Hsz + row * Hsz + (tid - 128)];
  if (r == 0) {
    c0 = st[1 * Bsz * Hsz + row * Hsz + j];
    c1 = st[3 * Bsz * Hsz + row * Hsz + j];
  }
  const float b00 = b00v[tid], b0t = b0tv[tid], b1 = b1v[tid];
  const float Sc = (r == 2) ? 2.f : 1.f;
  const float Kc = (r == 2) ? 2.f : 1.f;
  const float Dc = (r == 2) ? -1.f : 0.f;
  __syncthreads();

  for (int t = 0; t < Ssz; ++t) {
    const h8* H0r = H0[t & 1];
    h8* H0w = H0[(t + 1) & 1];
    const h8* H1r = H1[t & 1];       // h1(t-1)
    // P1: cell0 gates; feedback y(t-1)@Wih0 == h1(t-1)@W' + b'
    float a[4] = {(t > 0) ? b0t : b00, 0.f, 0.f, 0.f};
    if (t > 0) {
#pragma unroll
      for (int k = 0; k < 16; ++k) a[k & 3] = dot8(H1r[k], Wp[k], a[k & 3]);
    }
#pragma unroll
    for (int k = 0; k < 16; ++k) a[k & 3] = dot8(H0r[k], Whh0[k], a[k & 3]);
    float av = (a[0] + a[1]) + (a[2] + a[3]);
    float n = Sc * sigm(Kc * av) + Dc;
    float vf = qperm<0xB1, 1>(n), vg = qperm<0x4E, 2>(n), vo = qperm<0x1B, 3>(n);
    if (r == 0) {
      c0 = vf * c0 + n * vg;
      ((_Float16*)H0w)[j] = (_Float16)(vo * tanh_f(c0));
    }
    __syncthreads();
    // P2: cell1 gates
    h8* H1w = H1[(t + 1) & 1];
    float a1[4] = {b1, 0.f, 0.f, 0.f};
#pragma unroll
    for (int k = 0; k < 16; ++k) a1[k & 3] = dot8(H0w[k], Wih1[k], a1[k & 3]);
#pragma unroll
    for (int k = 0; k < 16; ++k) a1[k & 3] = dot8(H1r[k], s_whh1[k * G4 + tid], a1[k & 3]);
    av = (a1[0] + a1[1]) + (a1[2] + a1[3]);
    n = Sc * sigm(Kc * av) + Dc;
    vf = qperm<0xB1, 1>(n); vg = qperm<0x4E, 2>(n); vo = qperm<0x1B, 3>(n);
    if (r == 0) {
      c1 = vf * c1 + n * vg;
      float h = vo * tanh_f(c1);
      ((_Float16*)H1w)[j] = (_Float16)h;
      h1g[((size_t)row * Ssz + t) * Hsz + j] = (_Float16)h;  // for epilogue fc
    }
    __syncthreads();
  }
}

// Epilogue: out[rowt][j] = fcb[j] + h1[rowt] . fcW[j]  (in-place: h1 f16 bytes
// occupy exactly the same 256B/rowt region of d_out that the f32 outputs will).
__global__ void __launch_bounds__(256)
out_kernel(const float* __restrict__ fcw, const float* __restrict__ fcb,
           float* __restrict__ out) {
  __shared__ h8 s_fc[64][17];        // padded: avoid 16-way bank conflict
  __shared__ h8 s_h[64][16];
  const int tid = threadIdx.x;
  const size_t base = (size_t)blockIdx.x * 64;   // rowt base
  const h8* h1g = (const h8*)out;
#pragma unroll
  for (int i = 0; i < 4; ++i) {
    int idx = tid + 256 * i;         // 1024 h8 entries = 64 rows x 16
    s_h[idx >> 4][idx & 15] = h1g[base * 16 + idx];
  }
#pragma unroll
  for (int i = 0; i < 4; ++i) {
    int idx = tid + 256 * i;         // j = idx>>4, k8 = idx&15
    int jj = idx >> 4, k8 = idx & 15;
    h8 v;
#pragma unroll
    for (int e = 0; e < 8; ++e) v[e] = (_Float16)fcw[jj * 128 + k8 * 8 + e];
    s_fc[jj][k8] = v;
  }
  __syncthreads();
  const int j = tid & 63, rg = tid >> 6;
  const float bj = fcb[j];
#pragma unroll
  for (int i = 0; i < 16; ++i) {
    int rr = rg * 16 + i;
    float a0 = 0.f, a1 = 0.f;
#pragma unroll
    for (int k = 0; k < 16; k += 2) {
      a0 = dot8(s_h[rr][k], s_fc[j][k], a0);
      a1 = dot8(s_h[rr][k + 1], s_fc[j][k + 1], a1);
    }
    out[(base + rr) * 64 + j] = bj + a0 + a1;
  }
}

// ---- prep kernels ----

// fp32 [512][K] row-major -> f16 h8 [K/8][512], gate-interleaved column perm
__global__ void pack8p_kernel(const float* __restrict__ W, h8* __restrict__ o, int K) {
  int idx = blockIdx.x * 256 + threadIdx.x;
  int tot = (K >> 3) * G4;
  if (idx >= tot) return;
  int k8 = idx >> 9, np = idx & 511;
  const float* p = W + permcol(np) * K + 8 * k8;
  h8 v;
#pragma unroll
  for (int e = 0; e < 8; ++e) v[e] = (_Float16)p[e];
  o[idx] = v;
}

// W'[h][col] = sum_d Wih0_dec[col][d] * fcW[d][h]; packed [16][512] h8, permuted cols
__global__ void wprime_kernel(const float* __restrict__ wih0d, const float* __restrict__ fcw,
                              h8* __restrict__ o) {
  int idx = blockIdx.x * 256 + threadIdx.x;
  if (idx >= 16 * G4) return;
  int k8 = idx >> 9, np = idx & 511;
  int col = permcol(np);
  h8 v;
#pragma unroll
  for (int e = 0; e < 8; ++e) {
    int h = 8 * k8 + e;
    float s = 0.f;
    for (int d = 0; d < 64; ++d) s += wih0d[col * 64 + d] * fcw[d * 128 + h];
    v[e] = (_Float16)s;
  }
  o[idx] = v;
}

__global__ void biasp_kernel(const float* __restrict__ a, const float* __restrict__ b,
                             float* __restrict__ o) {
  int n = blockIdx.x * 256 + threadIdx.x;
  if (n >= G4) return;
  int c = permcol(n);
  o[n] = a[c] + b[c];
}

// b0t[n] = b00[n] + sum_d fcb[d]*Wih0_dec[permcol(n)][d]
__global__ void bprime_kernel(const float* __restrict__ b00, const float* __restrict__ wih0d,
                              const float* __restrict__ fcb, float* __restrict__ o) {
  int n = blockIdx.x * 256 + threadIdx.x;
  if (n >= G4) return;
  int c = permcol(n);
  float s = 0.f;
  for (int d = 0; d < 64; ++d) s += fcb[d] * wih0d[c * 64 + d];
  o[n] = b00[n] + s;
}

extern "C" void kernel_launch(void* const* d_in, const int* in_sizes, int n_in,
                              void* d_out, int out_size, void* d_ws, size_t ws_size,
                              hipStream_t stream) {
  (void)in_sizes; (void)n_in; (void)out_size; (void)ws_size;
  char* ws = (char*)d_ws;
  size_t off = 0;
  auto take = [&](size_t bytes) {
    char* p = ws + off;
    off += (bytes + 255) & ~(size_t)255;
    return p;
  };

  h8* e0_wih = (h8*)take(8 * 512 * 16);
  h8* e0_whh = (h8*)take(16 * 512 * 16);
  h8* e1_wih = (h8*)take(16 * 512 * 16);
  h8* e1_whh = (h8*)take(16 * 512 * 16);
  h8* d_wp   = (h8*)take(16 * 512 * 16);
  h8* d0_whh = (h8*)take(16 * 512 * 16);
  h8* d1_wih = (h8*)take(16 * 512 * 16);
  h8* d1_whh = (h8*)take(16 * 512 * 16);
  float* b_e0  = (float*)take(512 * 4);
  float* b_e1  = (float*)take(512 * 4);
  float* b_d00 = (float*)take(512 * 4);
  float* b_d0t = (float*)take(512 * 4);
  float* b_d1  = (float*)take(512 * 4);
  float* st    = (float*)take(4 * Bsz * Hsz * 4);

  const float* x = (const float*)d_in[0];

  pack8p_kernel<<<16, 256, 0, stream>>>((const float*)d_in[1], e0_wih, 64);
  pack8p_kernel<<<32, 256, 0, stream>>>((const float*)d_in[2], e0_whh, 128);
  pack8p_kernel<<<32, 256, 0, stream>>>((const float*)d_in[5], e1_wih, 128);
  pack8p_kernel<<<32, 256, 0, stream>>>((const float*)d_in[6], e1_whh, 128);
  wprime_kernel<<<32, 256, 0, stream>>>((const float*)d_in[9], (const float*)d_in[17], d_wp);
  pack8p_kernel<<<32, 256, 0, stream>>>((const float*)d_in[10], d0_whh, 128);
  pack8p_kernel<<<32, 256, 0, stream>>>((const float*)d_in[13], d1_wih, 128);
  pack8p_kernel<<<32, 256, 0, stream>>>((const float*)d_in[14], d1_whh, 128);

  biasp_kernel<<<2, 256, 0, stream>>>((const float*)d_in[3], (const float*)d_in[4], b_e0);
  biasp_kernel<<<2, 256, 0, stream>>>((const float*)d_in[7], (const float*)d_in[8], b_e1);
  biasp_kernel<<<2, 256, 0, stream>>>((const float*)d_in[11], (const float*)d_in[12], b_d00);
  biasp_kernel<<<2, 256, 0, stream>>>((const float*)d_in[15], (const float*)d_in[16], b_d1);
  bprime_kernel<<<2, 256, 0, stream>>>(b_d00, (const float*)d_in[9], (const float*)d_in[18], b_d0t);

  enc_kernel<<<Bsz, NT, 0, stream>>>(x, e0_wih, e0_whh, e1_wih, e1_whh, b_e0, b_e1, st);
  dec_kernel<<<Bsz, NT, 0, stream>>>(d_wp, d0_whh, d1_wih, d1_whh,
                                     b_d00, b_d0t, b_d1, st, (_Float16*)d_out);
  out_kernel<<<(Bsz * Ssz) / 64, 256, 0, stream>>>((const float*)d_in[17],
                                                   (const float*)d_in[18], (float*)d_out);
}

// Round 5
// 5479.119 us; speedup vs baseline: 1.1611x; 1.0136x over previous
//
#include <hip/hip_runtime.h>
#include <hip/hip_fp16.h>

// LSTM autoencoder B=256,S=512,D=64,H=128. 1 row/WG, 256 WGs, 512 thr = gate cols.
// Gate-interleaved columns: thread tid -> hidden j=tid>>2, gate r=tid&3 (i,f,g,o).
// Weights pinned in VGPRs via asm-pin (non-rematerializable) + 1 matrix in LDS.
// LDS >128KB forces 1 WG/CU -> 2 waves/SIMD -> 256-VGPR budget (no attr games).
// enc: x row fully staged in LDS (zero global in loop), 1 barrier/step.
// dec: H1 read once/step feeds both W' and Whh1 dots; 2 barriers/step.
// fc projection: separate epilogue kernel, in-place in d_out.

typedef _Float16 h2 __attribute__((ext_vector_type(2)));
typedef _Float16 h8 __attribute__((ext_vector_type(8)));
typedef float f4 __attribute__((ext_vector_type(4)));

#define Bsz 256
#define Ssz 512
#define Dsz 64
#define Hsz 128
#define G4 512
#define NT 512

__device__ __forceinline__ float fdot2f(h2 a, h2 b, float c) {
#if __has_builtin(__builtin_amdgcn_fdot2)
  return __builtin_amdgcn_fdot2(a, b, c, false);
#else
  return c + (float)a[0] * (float)b[0] + (float)a[1] * (float)b[1];
#endif
}

__device__ __forceinline__ float dot8(h8 v, h8 w, float acc) {
  h2 v0 = __builtin_shufflevector(v, v, 0, 1);
  h2 v1 = __builtin_shufflevector(v, v, 2, 3);
  h2 v2 = __builtin_shufflevector(v, v, 4, 5);
  h2 v3 = __builtin_shufflevector(v, v, 6, 7);
  h2 w0 = __builtin_shufflevector(w, w, 0, 1);
  h2 w1 = __builtin_shufflevector(w, w, 2, 3);
  h2 w2 = __builtin_shufflevector(w, w, 4, 5);
  h2 w3 = __builtin_shufflevector(w, w, 6, 7);
  acc = fdot2f(v0, w0, acc);
  acc = fdot2f(v1, w1, acc);
  acc = fdot2f(v2, w2, acc);
  acc = fdot2f(v3, w3, acc);
  return acc;
}

// Opaque identity: makes the loaded value non-rematerializable so the register
// allocator must keep it resident instead of sinking the load into the loop.
__device__ __forceinline__ void pin8(h8& v) {
  f4 f = __builtin_bit_cast(f4, v);
  asm volatile("" : "+v"(f));
  v = __builtin_bit_cast(h8, f);
}

__device__ __forceinline__ float sigm(float v) { return 1.f / (1.f + __expf(-v)); }
__device__ __forceinline__ float tanh_f(float v) { return 2.f / (1.f + __expf(-2.f * v)) - 1.f; }

// quad_perm DPP: 0xB1=[1,0,3,2](xor1), 0x4E=[2,3,0,1](xor2), 0x1B=[3,2,1,0](xor3)
template <int C, int M>
__device__ __forceinline__ float qperm(float x) {
#if __has_builtin(__builtin_amdgcn_mov_dpp)
  int i = __builtin_amdgcn_mov_dpp(__builtin_bit_cast(int, x), C, 0xf, 0xf, true);
  return __builtin_bit_cast(float, i);
#else
  return __shfl_xor(x, M, 64);
#endif
}

__device__ __forceinline__ int permcol(int n) { return (n & 3) * 128 + (n >> 2); }

__global__ void __launch_bounds__(NT)
enc_kernel(const float* __restrict__ x,
           const h8* __restrict__ wih0, const h8* __restrict__ whh0,
           const h8* __restrict__ wih1, const h8* __restrict__ whh1,
           const float* __restrict__ b0v, const float* __restrict__ b1v,
           float* __restrict__ st) {
  __shared__ h8 s_wih0[8 * G4];        // 64 KiB
  __shared__ h8 sx[Ssz * 8];           // 64 KiB: whole x row as f16
  __shared__ h8 H0[2][16], H1[2][16];  // total LDS ~133 KiB -> 1 WG/CU

  const int tid = threadIdx.x;
  const int row = blockIdx.x;
  const int r = tid & 3;
  const int j = tid >> 2;

  h8 Whh0[16], Wih1[16], Whh1[16];     // 192 VGPRs, pinned
#pragma unroll
  for (int k = 0; k < 16; ++k) { Whh0[k] = whh0[k * G4 + tid]; pin8(Whh0[k]); }
#pragma unroll
  for (int k = 0; k < 16; ++k) { Wih1[k] = wih1[k * G4 + tid]; pin8(Wih1[k]); }
#pragma unroll
  for (int k = 0; k < 16; ++k) { Whh1[k] = whh1[k * G4 + tid]; pin8(Whh1[k]); }
  for (int i = tid; i < 8 * G4; i += NT) s_wih0[i] = wih0[i];
  {  // stage full x row -> f16 LDS
    const float* xr = x + (size_t)row * (Ssz * Dsz);
    _Float16* sxp = (_Float16*)sx;
    for (int e = tid; e < Ssz * Dsz; e += NT) sxp[e] = (_Float16)xr[e];
  }
  if (tid < 128) ((_Float16*)H0[0])[tid] = (_Float16)0.f;
  else if (tid < 256) ((_Float16*)H1[0])[tid - 128] = (_Float16)0.f;

  const float b0 = b0v[tid], b1 = b1v[tid];
  const float Sc = (r == 2) ? 2.f : 1.f;
  const float Kc = (r == 2) ? 2.f : 1.f;
  const float Dc = (r == 2) ? -1.f : 0.f;
  float c0 = 0.f, c1 = 0.f;
  __syncthreads();

  for (int t = 0; t < Ssz; ++t) {
    const h8* H0r = H0[t & 1];
    h8* H0w = H0[(t + 1) & 1];
    // P1: layer0 gates
    float a[4] = {b0, 0.f, 0.f, 0.f};
#pragma unroll
    for (int k = 0; k < 8; ++k) a[k & 3] = dot8(sx[t * 8 + k], s_wih0[k * G4 + tid], a[k & 3]);
#pragma unroll
    for (int k = 0; k < 16; ++k) a[k & 3] = dot8(H0r[k], Whh0[k], a[k & 3]);
    float av = (a[0] + a[1]) + (a[2] + a[3]);
    float n = Sc * sigm(Kc * av) + Dc;
    float vf = qperm<0xB1, 1>(n), vg = qperm<0x4E, 2>(n), vo = qperm<0x1B, 3>(n);
    if (r == 0) {
      c0 = vf * c0 + n * vg;
      ((_Float16*)H0w)[j] = (_Float16)(vo * tanh_f(c0));
    }
    __syncthreads();
    // P2: layer1 gates
    const h8* H1r = H1[t & 1];
    h8* H1w = H1[(t + 1) & 1];
    float a1[4] = {b1, 0.f, 0.f, 0.f};
#pragma unroll
    for (int k = 0; k < 16; ++k) a1[k & 3] = dot8(H0w[k], Wih1[k], a1[k & 3]);
#pragma unroll
    for (int k = 0; k < 16; ++k) a1[k & 3] = dot8(H1r[k], Whh1[k], a1[k & 3]);
    av = (a1[0] + a1[1]) + (a1[2] + a1[3]);
    n = Sc * sigm(Kc * av) + Dc;
    vf = qperm<0xB1, 1>(n); vg = qperm<0x4E, 2>(n); vo = qperm<0x1B, 3>(n);
    if (r == 0) {
      c1 = vf * c1 + n * vg;
      ((_Float16*)H1w)[j] = (_Float16)(vo * tanh_f(c1));
    }
    // no barrier: all P2 writes are ordered by next step's P1 barrier
  }
  if (r == 0) {
    st[0 * Bsz * Hsz + row * Hsz + j] = (float)((_Float16*)H0[Ssz & 1])[j];
    st[1 * Bsz * Hsz + row * Hsz + j] = c0;
    st[2 * Bsz * Hsz + row * Hsz + j] = (float)((_Float16*)H1[Ssz & 1])[j];
    st[3 * Bsz * Hsz + row * Hsz + j] = c1;
  }
}

__global__ void __launch_bounds__(NT)
dec_kernel(const h8* __restrict__ wprime, const h8* __restrict__ whh0,
           const h8* __restrict__ wih1, const h8* __restrict__ whh1,
           const float* __restrict__ b00v, const float* __restrict__ b0tv,
           const float* __restrict__ b1v, const float* __restrict__ st,
           _Float16* __restrict__ h1g) {
  __shared__ h8 s_whh1[16 * G4];       // 128 KiB -> 1 WG/CU
  __shared__ h8 H0[2][16], H1[2][16];

  const int tid = threadIdx.x;
  const int row = blockIdx.x;
  const int r = tid & 3;
  const int j = tid >> 2;

  h8 Wp[16], Whh0[16], Wih1[16];       // 192 VGPRs, pinned
#pragma unroll
  for (int k = 0; k < 16; ++k) { Wp[k] = wprime[k * G4 + tid]; pin8(Wp[k]); }
#pragma unroll
  for (int k = 0; k < 16; ++k) { Whh0[k] = whh0[k * G4 + tid]; pin8(Whh0[k]); }
#pragma unroll
  for (int k = 0; k < 16; ++k) { Wih1[k] = wih1[k * G4 + tid]; pin8(Wih1[k]); }
  for (int i = tid; i < 16 * G4; i += NT) s_whh1[i] = whh1[i];

  float c0 = 0.f, c1 = 0.f;
  if (tid < 128)
    ((_Float16*)H0[0])[tid] = (_Float16)st[0 * Bsz * Hsz + row * Hsz + tid];
  else if (tid < 256)
    ((_Float16*)H1[0])[tid - 128] = (_Float16)st[2 * Bsz * Hsz + row * Hsz + (tid - 128)];
  if (r == 0) {
    c0 = st[1 * Bsz * Hsz + row * Hsz + j];
    c1 = st[3 * Bsz * Hsz + row * Hsz + j];
  }
  const float b00 = b00v[tid], b0t = b0tv[tid], b1 = b1v[tid];
  const float Sc = (r == 2) ? 2.f : 1.f;
  const float Kc = (r == 2) ? 2.f : 1.f;
  const float Dc = (r == 2) ? -1.f : 0.f;
  __syncthreads();

  for (int t = 0; t < Ssz; ++t) {
    const h8* H0r = H0[t & 1];
    h8* H0w = H0[(t + 1) & 1];
    const h8* H1r = H1[t & 1];         // h1(t-1); read ONCE, feeds W' and Whh1
    // P1: cell0 gates + Whh1 partial for cell1
    float a[4] = {(t > 0) ? b0t : b00, 0.f, 0.f, 0.f};
    float a1[2] = {b1, 0.f};
    if (t > 0) {
#pragma unroll
      for (int k = 0; k < 16; ++k) {
        h8 hv = H1r[k];
        a[k & 3] = dot8(hv, Wp[k], a[k & 3]);             // y(t-1)@Wih0 via W'
        a1[k & 1] = dot8(hv, s_whh1[k * G4 + tid], a1[k & 1]);
      }
    } else {
#pragma unroll
      for (int k = 0; k < 16; ++k)
        a1[k & 1] = dot8(H1r[k], s_whh1[k * G4 + tid], a1[k & 1]);
    }
#pragma unroll
    for (int k = 0; k < 16; ++k) a[k & 3] = dot8(H0r[k], Whh0[k], a[k & 3]);
    float av = (a[0] + a[1]) + (a[2] + a[3]);
    float n = Sc * sigm(Kc * av) + Dc;
    float vf = qperm<0xB1, 1>(n), vg = qperm<0x4E, 2>(n), vo = qperm<0x1B, 3>(n);
    if (r == 0) {
      c0 = vf * c0 + n * vg;
      ((_Float16*)H0w)[j] = (_Float16)(vo * tanh_f(c0));
    }
    __syncthreads();
    // P2: finish cell1 gates
    h8* H1w = H1[(t + 1) & 1];
#pragma unroll
    for (int k = 0; k < 16; ++k) a1[k & 1] = dot8(H0w[k], Wih1[k], a1[k & 1]);
    av = a1[0] + a1[1];
    n = Sc * sigm(Kc * av) + Dc;
    vf = qperm<0xB1, 1>(n); vg = qperm<0x4E, 2>(n); vo = qperm<0x1B, 3>(n);
    if (r == 0) {
      c1 = vf * c1 + n * vg;
      float h = vo * tanh_f(c1);
      ((_Float16*)H1w)[j] = (_Float16)h;
      h1g[((size_t)row * Ssz + t) * Hsz + j] = (_Float16)h;  // epilogue fc input
    }
    __syncthreads();
  }
}

// Epilogue: out[rowt][j] = fcb[j] + h1[rowt].fcW[j]; in-place over d_out.
__global__ void __launch_bounds__(256)
out_kernel(const float* __restrict__ fcw, const float* __restrict__ fcb,
           float* __restrict__ out) {
  __shared__ h8 s_fc[64][17];
  __shared__ h8 s_h[64][16];
  const int tid = threadIdx.x;
  const size_t base = (size_t)blockIdx.x * 64;
  const h8* h1g = (const h8*)out;
#pragma unroll
  for (int i = 0; i < 4; ++i) {
    int idx = tid + 256 * i;
    s_h[idx >> 4][idx & 15] = h1g[base * 16 + idx];
  }
#pragma unroll
  for (int i = 0; i < 4; ++i) {
    int idx = tid + 256 * i;
    int jj = idx >> 4, k8 = idx & 15;
    h8 v;
#pragma unroll
    for (int e = 0; e < 8; ++e) v[e] = (_Float16)fcw[jj * 128 + k8 * 8 + e];
    s_fc[jj][k8] = v;
  }
  __syncthreads();
  const int j = tid & 63, rg = tid >> 6;
  const float bj = fcb[j];
#pragma unroll
  for (int i = 0; i < 16; ++i) {
    int rr = rg * 16 + i;
    float a0 = 0.f, a1 = 0.f;
#pragma unroll
    for (int k = 0; k < 16; k += 2) {
      a0 = dot8(s_h[rr][k], s_fc[j][k], a0);
      a1 = dot8(s_h[rr][k + 1], s_fc[j][k + 1], a1);
    }
    out[(base + rr) * 64 + j] = bj + a0 + a1;
  }
}

// ---- prep kernels ----

__global__ void pack8p_kernel(const float* __restrict__ W, h8* __restrict__ o, int K) {
  int idx = blockIdx.x * 256 + threadIdx.x;
  int tot = (K >> 3) * G4;
  if (idx >= tot) return;
  int k8 = idx >> 9, np = idx & 511;
  const float* p = W + permcol(np) * K + 8 * k8;
  h8 v;
#pragma unroll
  for (int e = 0; e < 8; ++e) v[e] = (_Float16)p[e];
  o[idx] = v;
}

__global__ void wprime_kernel(const float* __restrict__ wih0d, const float* __restrict__ fcw,
                              h8* __restrict__ o) {
  int idx = blockIdx.x * 256 + threadIdx.x;
  if (idx >= 16 * G4) return;
  int k8 = idx >> 9, np = idx & 511;
  int col = permcol(np);
  h8 v;
#pragma unroll
  for (int e = 0; e < 8; ++e) {
    int h = 8 * k8 + e;
    float s = 0.f;
    for (int d = 0; d < 64; ++d) s += wih0d[col * 64 + d] * fcw[d * 128 + h];
    v[e] = (_Float16)s;
  }
  o[idx] = v;
}

__global__ void biasp_kernel(const float* __restrict__ a, const float* __restrict__ b,
                             float* __restrict__ o) {
  int n = blockIdx.x * 256 + threadIdx.x;
  if (n >= G4) return;
  int c = permcol(n);
  o[n] = a[c] + b[c];
}

__global__ void bprime_kernel(const float* __restrict__ b00, const float* __restrict__ wih0d,
                              const float* __restrict__ fcb, float* __restrict__ o) {
  int n = blockIdx.x * 256 + threadIdx.x;
  if (n >= G4) return;
  int c = permcol(n);
  float s = 0.f;
  for (int d = 0; d < 64; ++d) s += fcb[d] * wih0d[c * 64 + d];
  o[n] = b00[n] + s;
}

extern "C" void kernel_launch(void* const* d_in, const int* in_sizes, int n_in,
                              void* d_out, int out_size, void* d_ws, size_t ws_size,
                              hipStream_t stream) {
  (void)in_sizes; (void)n_in; (void)out_size; (void)ws_size;
  char* ws = (char*)d_ws;
  size_t off = 0;
  auto take = [&](size_t bytes) {
    char* p = ws + off;
    off += (bytes + 255) & ~(size_t)255;
    return p;
  };

  h8* e0_wih = (h8*)take(8 * 512 * 16);
  h8* e0_whh = (h8*)take(16 * 512 * 16);
  h8* e1_wih = (h8*)take(16 * 512 * 16);
  h8* e1_whh = (h8*)take(16 * 512 * 16);
  h8* d_wp   = (h8*)take(16 * 512 * 16);
  h8* d0_whh = (h8*)take(16 * 512 * 16);
  h8* d1_wih = (h8*)take(16 * 512 * 16);
  h8* d1_whh = (h8*)take(16 * 512 * 16);
  float* b_e0  = (float*)take(512 * 4);
  float* b_e1  = (float*)take(512 * 4);
  float* b_d00 = (float*)take(512 * 4);
  float* b_d0t = (float*)take(512 * 4);
  float* b_d1  = (float*)take(512 * 4);
  float* st    = (float*)take(4 * Bsz * Hsz * 4);

  const float* x = (const float*)d_in[0];

  pack8p_kernel<<<16, 256, 0, stream>>>((const float*)d_in[1], e0_wih, 64);
  pack8p_kernel<<<32, 256, 0, stream>>>((const float*)d_in[2], e0_whh, 128);
  pack8p_kernel<<<32, 256, 0, stream>>>((const float*)d_in[5], e1_wih, 128);
  pack8p_kernel<<<32, 256, 0, stream>>>((const float*)d_in[6], e1_whh, 128);
  wprime_kernel<<<32, 256, 0, stream>>>((const float*)d_in[9], (const float*)d_in[17], d_wp);
  pack8p_kernel<<<32, 256, 0, stream>>>((const float*)d_in[10], d0_whh, 128);
  pack8p_kernel<<<32, 256, 0, stream>>>((const float*)d_in[13], d1_wih, 128);
  pack8p_kernel<<<32, 256, 0, stream>>>((const float*)d_in[14], d1_whh, 128);

  biasp_kernel<<<2, 256, 0, stream>>>((const float*)d_in[3], (const float*)d_in[4], b_e0);
  biasp_kernel<<<2, 256, 0, stream>>>((const float*)d_in[7], (const float*)d_in[8], b_e1);
  biasp_kernel<<<2, 256, 0, stream>>>((const float*)d_in[11], (const float*)d_in[12], b_d00);
  biasp_kernel<<<2, 256, 0, stream>>>((const float*)d_in[15], (const float*)d_in[16], b_d1);
  bprime_kernel<<<2, 256, 0, stream>>>(b_d00, (const float*)d_in[9], (const float*)d_in[18], b_d0t);

  enc_kernel<<<Bsz, NT, 0, stream>>>(x, e0_wih, e0_whh, e1_wih, e1_whh, b_e0, b_e1, st);
  dec_kernel<<<Bsz, NT, 0, stream>>>(d_wp, d0_whh, d1_wih, d1_whh,
                                     b_d00, b_d0t, b_d1, st, (_Float16*)d_out);
  out_kernel<<<(Bsz * Ssz) / 64, 256, 0, stream>>>((const float*)d_in[17],
                                                   (const float*)d_in[18], (float*)d_out);
}